// Round 1
// baseline (46.169 us; speedup 1.0000x reference)
//
#include <hip/hip_runtime.h>

#define NB 4
#define NV 4096
#define NF 8192
#define NP 6
#define NE 2048

// ---------------------------------------------------------------------------
// Kernel 1: projection. One thread per (b,p,v). Writes float2 (x,y) to ws.
// Also zeroes the chamfer accumulators out[0..3] (block 0 only) so the
// chamfer kernel can atomicAdd into them.
// ---------------------------------------------------------------------------
__global__ __launch_bounds__(256) void proj_kernel(const float* __restrict__ xs,
                                                   const float* __restrict__ pm,
                                                   float2* __restrict__ xyb,
                                                   float* __restrict__ out) {
    int t = blockIdx.x * 256 + threadIdx.x;          // t < NB*NP*NV
    if (blockIdx.x == 0 && threadIdx.x < 4) out[threadIdx.x] = 0.f;

    int v  = t & (NV - 1);
    int pp = t >> 12;            // b*NP + p   (NV = 2^12)
    int p  = pp % NP;
    int b  = pp / NP;

    const float* x3 = xs + (size_t)(b * NV + v) * 3;
    float x = x3[0], y = x3[1], z = x3[2];
    const float* M = pm + p * 12;
    float px = M[0] * x + M[1] * y + M[2]  * z + M[3];
    float py = M[4] * x + M[5] * y + M[6]  * z + M[7];
    float pz = M[8] * x + M[9] * y + M[10] * z + M[11];
    float inv = 1.0f / pz;
    xyb[t] = make_float2(px * inv, py * inv);
}

// ---------------------------------------------------------------------------
// Kernel 2: chamfer. Edges live in registers (32/lane x {ax,ay,c}); points
// are wave-uniform (scalar loads). Per point: 64 FMA + ~19 min + butterfly.
// grid = NB*NP*32 = 768 blocks x 4 waves = 3072 waves = 3/SIMD (balanced).
// ---------------------------------------------------------------------------
__global__ __launch_bounds__(256) void chamfer_kernel(const float* __restrict__ edgemaps,
                                                      const float2* __restrict__ xyb,
                                                      float* __restrict__ out) {
    int bid   = blockIdx.x;
    int chunk = bid & 31;        // 32 chunks of 128 points
    int pp    = bid >> 5;        // b*NP + p
    int lane  = threadIdx.x & 63;
    int w     = __builtin_amdgcn_readfirstlane(threadIdx.x >> 6);

    // Load this (b,p)'s edge table: lane holds edges {64k + lane}, k=0..31.
    const float2* em2 = (const float2*)edgemaps + (size_t)pp * NE;
    float ax[32], ay[32], cc[32];
#pragma unroll
    for (int k = 0; k < 32; ++k) {
        float2 e = em2[k * 64 + lane];
        ax[k] = -2.0f * e.x;
        ay[k] = -2.0f * e.y;
        cc[k] = e.x * e.x + e.y * e.y;
    }

    const float2* xy = xyb + (size_t)pp * NV + chunk * 128 + w * 32;

    float wsum = 0.0f;
    for (int q = 0; q < 32; ++q) {
        float2 pt = xy[q];               // wave-uniform -> s_load
        float X = pt.x, Y = pt.y;

        float d0 = fmaf(ay[0], Y, fmaf(ax[0], X, cc[0]));
        float d1 = fmaf(ay[1], Y, fmaf(ax[1], X, cc[1]));
        float d2 = fmaf(ay[2], Y, fmaf(ax[2], X, cc[2]));
        float d3 = fmaf(ay[3], Y, fmaf(ax[3], X, cc[3]));
        float d4 = fmaf(ay[4], Y, fmaf(ax[4], X, cc[4]));
        float d5 = fmaf(ay[5], Y, fmaf(ax[5], X, cc[5]));
        float d6 = fmaf(ay[6], Y, fmaf(ax[6], X, cc[6]));
        float d7 = fmaf(ay[7], Y, fmaf(ax[7], X, cc[7]));
        float m0 = fminf(d0, d1);
        float m1 = fminf(d2, d3);
        float m2 = fminf(d4, d5);
        float m3 = fminf(d6, d7);
#pragma unroll
        for (int k = 8; k < 32; k += 8) {
            float e0 = fmaf(ay[k + 0], Y, fmaf(ax[k + 0], X, cc[k + 0]));
            float e1 = fmaf(ay[k + 1], Y, fmaf(ax[k + 1], X, cc[k + 1]));
            float e2 = fmaf(ay[k + 2], Y, fmaf(ax[k + 2], X, cc[k + 2]));
            float e3 = fmaf(ay[k + 3], Y, fmaf(ax[k + 3], X, cc[k + 3]));
            float e4 = fmaf(ay[k + 4], Y, fmaf(ax[k + 4], X, cc[k + 4]));
            float e5 = fmaf(ay[k + 5], Y, fmaf(ax[k + 5], X, cc[k + 5]));
            float e6 = fmaf(ay[k + 6], Y, fmaf(ax[k + 6], X, cc[k + 6]));
            float e7 = fmaf(ay[k + 7], Y, fmaf(ax[k + 7], X, cc[k + 7]));
            m0 = fminf(fminf(m0, e0), e1);   // -> v_min3_f32
            m1 = fminf(fminf(m1, e2), e3);
            m2 = fminf(fminf(m2, e4), e5);
            m3 = fminf(fminf(m3, e6), e7);
        }
        float m = fminf(fminf(m0, m1), fminf(m2, m3));

        // 64-lane butterfly min
#pragma unroll
        for (int off = 1; off < 64; off <<= 1)
            m = fminf(m, __shfl_xor(m, off));

        wsum += m + (X * X + Y * Y);        // add back x2 after the min
    }

    __shared__ float red[4];
    if (lane == 0) red[w] = wsum;
    __syncthreads();
    if (threadIdx.x == 0) {
        float tsum = red[0] + red[1] + red[2] + red[3];
        atomicAdd(&out[pp / NP], tsum * (1.0f / (NP * NV)));
    }
}

// ---------------------------------------------------------------------------
// Kernel 3: signed volume. One block per batch; deterministic tree reduce.
// ---------------------------------------------------------------------------
__global__ __launch_bounds__(256) void vol_kernel(const float* __restrict__ xs,
                                                  const int* __restrict__ faces,
                                                  const float* __restrict__ tv,
                                                  float* __restrict__ out) {
    int b = blockIdx.x;
    int tid = threadIdx.x;
    float s = 0.0f;
    for (int f = tid; f < NF; f += 256) {
        const int* fp = faces + (size_t)(b * NF + f) * 3;
        int i0 = fp[0], i1 = fp[1], i2 = fp[2];
        const float* p0 = xs + (size_t)(b * NV + i0) * 3;
        const float* p1 = xs + (size_t)(b * NV + i1) * 3;
        const float* p2 = xs + (size_t)(b * NV + i2) * 3;
        float ax = p0[0], ayy = p0[1], az = p0[2];
        float bx = p1[0], by = p1[1], bz = p1[2];
        float cx = p2[0], cy = p2[1], cz = p2[2];
        float crx = ayy * bz - az * by;
        float cry = az * bx - ax * bz;
        float crz = ax * by - ayy * bx;
        s += (crx * cx + cry * cy + crz * cz) * (1.0f / 6.0f);
    }
    __shared__ float red[256];
    red[tid] = s;
    __syncthreads();
    for (int st = 128; st > 0; st >>= 1) {
        if (tid < st) red[tid] += red[tid + st];
        __syncthreads();
    }
    if (tid == 0) {
        float vol = fabsf(red[0]);
        float d = vol - tv[b];
        out[4 + b] = d * d;
    }
}

// ---------------------------------------------------------------------------
extern "C" void kernel_launch(void* const* d_in, const int* in_sizes, int n_in,
                              void* d_out, int out_size, void* d_ws, size_t ws_size,
                              hipStream_t stream) {
    const float* xs    = (const float*)d_in[0];
    const float* pm    = (const float*)d_in[1];
    const float* em    = (const float*)d_in[2];
    const int*   faces = (const int*)d_in[3];
    const float* tv    = (const float*)d_in[4];
    float* out = (float*)d_out;
    float2* xyb = (float2*)d_ws;   // NB*NP*NV float2 = 786 KB

    proj_kernel<<<(NB * NP * NV) / 256, 256, 0, stream>>>(xs, pm, xyb, out);
    chamfer_kernel<<<NB * NP * 32, 256, 0, stream>>>(em, xyb, out);
    vol_kernel<<<NB, 256, 0, stream>>>(xs, faces, tv, out);
}

// Round 2
// 25.566 us; speedup vs baseline: 1.8059x; 1.8059x over previous
//
#include <hip/hip_runtime.h>

#define NB 4
#define NV 4096
#define NF 8192
#define NP 6
#define NE 2048

#define VOL_BLOCKS   32                 // 8 per batch, 1024 faces each
#define CHAM_BLOCKS  (NB * NP * 32)     // 768: 32 chunks of 128 points per (b,p)
#define FACES_PER_VB (NF / 8)           // 1024

// ---------------------------------------------------------------------------
// Fused kernel. Blocks [0,32): volume partials. Blocks [32,800): chamfer
// chunks (projection computed in-block into LDS, edges in registers).
// Each block writes one float partial to ws (pure store -> no init needed).
//   ws[0..767]   : chamfer partial for chunk cb  (cb = pp*32 + chunk)
//   ws[768..799] : volume partial for vol block
// ---------------------------------------------------------------------------
__global__ __launch_bounds__(256, 3) void fused_kernel(
    const float* __restrict__ xs,
    const float* __restrict__ pm,
    const float* __restrict__ em,
    const int*   __restrict__ faces,
    float* __restrict__ ws)
{
    __shared__ float  red[256];
    __shared__ float2 sxy[128];

    const int bid = blockIdx.x;
    const int tid = threadIdx.x;

    if (bid < VOL_BLOCKS) {
        // ---------------- volume partial: 1024 faces ----------------
        const int b   = bid >> 3;
        const int sub = bid & 7;
        float s = 0.0f;
#pragma unroll
        for (int i = 0; i < 4; ++i) {
            int f = sub * FACES_PER_VB + i * 256 + tid;
            const int* fp = faces + (size_t)(b * NF + f) * 3;
            int i0 = fp[0], i1 = fp[1], i2 = fp[2];
            const float* p0 = xs + (size_t)(b * NV + i0) * 3;
            const float* p1 = xs + (size_t)(b * NV + i1) * 3;
            const float* p2 = xs + (size_t)(b * NV + i2) * 3;
            float a0 = p0[0], a1 = p0[1], a2 = p0[2];
            float b0 = p1[0], b1 = p1[1], b2 = p1[2];
            float c0 = p2[0], c1 = p2[1], c2 = p2[2];
            float crx = a1 * b2 - a2 * b1;
            float cry = a2 * b0 - a0 * b2;
            float crz = a0 * b1 - a1 * b0;
            s += crx * c0 + cry * c1 + crz * c2;
        }
        red[tid] = s * (1.0f / 6.0f);
        __syncthreads();
        for (int st = 128; st > 0; st >>= 1) {
            if (tid < st) red[tid] += red[tid + st];
            __syncthreads();
        }
        if (tid == 0) ws[CHAM_BLOCKS + bid] = red[0];
        return;
    }

    // ---------------- chamfer chunk: 128 points x 2048 edges ----------------
    const int cb    = bid - VOL_BLOCKS;   // 0..767
    const int chunk = cb & 31;
    const int pp    = cb >> 5;            // b*NP + p
    const int p     = pp % NP;
    const int b     = pp / NP;
    const int lane  = tid & 63;
    const int w     = tid >> 6;

    // Project this chunk's 128 points into LDS.
    if (tid < 128) {
        int v = chunk * 128 + tid;
        const float* x3 = xs + (size_t)(b * NV + v) * 3;
        float x = x3[0], y = x3[1], z = x3[2];
        const float* M = pm + p * 12;                     // uniform -> s_load
        float px = fmaf(M[0], x, fmaf(M[1], y, fmaf(M[2],  z, M[3])));
        float py = fmaf(M[4], x, fmaf(M[5], y, fmaf(M[6],  z, M[7])));
        float pz = fmaf(M[8], x, fmaf(M[9], y, fmaf(M[10], z, M[11])));
        float inv = 1.0f / pz;
        sxy[tid] = make_float2(px * inv, py * inv);
    }

    // Edge table into registers: lane holds 32 of the 2048 edges
    // (assignment is arbitrary; min over all lanes covers every edge once).
    const float4* em4 = (const float4*)em + (size_t)pp * (NE / 2);
    float ax[32], ay[32], cc[32];
#pragma unroll
    for (int k = 0; k < 16; ++k) {
        float4 e = em4[k * 64 + lane];
        ax[2 * k]     = -2.0f * e.x;
        ay[2 * k]     = -2.0f * e.y;
        cc[2 * k]     = fmaf(e.x, e.x, e.y * e.y);
        ax[2 * k + 1] = -2.0f * e.z;
        ay[2 * k + 1] = -2.0f * e.w;
        cc[2 * k + 1] = fmaf(e.z, e.z, e.w * e.w);
    }
    __syncthreads();

    float wsum = 0.0f;
#pragma unroll 2
    for (int q = 0; q < 32; ++q) {
        float2 pt = sxy[w * 32 + q];      // uniform LDS broadcast
        float X = pt.x, Y = pt.y;

        float t0 = fmaf(ay[0], Y, fmaf(ax[0], X, cc[0]));
        float t1 = fmaf(ay[1], Y, fmaf(ax[1], X, cc[1]));
        float m0 = fminf(t0, t1);
        t0 = fmaf(ay[2], Y, fmaf(ax[2], X, cc[2]));
        t1 = fmaf(ay[3], Y, fmaf(ax[3], X, cc[3]));
        float m1 = fminf(t0, t1);
        t0 = fmaf(ay[4], Y, fmaf(ax[4], X, cc[4]));
        t1 = fmaf(ay[5], Y, fmaf(ax[5], X, cc[5]));
        float m2 = fminf(t0, t1);
        t0 = fmaf(ay[6], Y, fmaf(ax[6], X, cc[6]));
        t1 = fmaf(ay[7], Y, fmaf(ax[7], X, cc[7]));
        float m3 = fminf(t0, t1);
#pragma unroll
        for (int k = 8; k < 32; k += 8) {
            t0 = fmaf(ay[k + 0], Y, fmaf(ax[k + 0], X, cc[k + 0]));
            t1 = fmaf(ay[k + 1], Y, fmaf(ax[k + 1], X, cc[k + 1]));
            m0 = fminf(fminf(m0, t0), t1);                 // v_min3_f32
            t0 = fmaf(ay[k + 2], Y, fmaf(ax[k + 2], X, cc[k + 2]));
            t1 = fmaf(ay[k + 3], Y, fmaf(ax[k + 3], X, cc[k + 3]));
            m1 = fminf(fminf(m1, t0), t1);
            t0 = fmaf(ay[k + 4], Y, fmaf(ax[k + 4], X, cc[k + 4]));
            t1 = fmaf(ay[k + 5], Y, fmaf(ax[k + 5], X, cc[k + 5]));
            m2 = fminf(fminf(m2, t0), t1);
            t0 = fmaf(ay[k + 6], Y, fmaf(ax[k + 6], X, cc[k + 6]));
            t1 = fmaf(ay[k + 7], Y, fmaf(ax[k + 7], X, cc[k + 7]));
            m3 = fminf(fminf(m3, t0), t1);
        }
        float m = fminf(fminf(m0, m1), fminf(m2, m3));

        // 64-lane butterfly min
#pragma unroll
        for (int off = 1; off < 64; off <<= 1)
            m = fminf(m, __shfl_xor(m, off));

        wsum += m + fmaf(X, X, Y * Y);    // add x^2 back after the min
    }

    if (lane == 0) red[w] = wsum;
    __syncthreads();
    if (tid == 0) ws[cb] = (red[0] + red[1]) + (red[2] + red[3]);
}

// ---------------------------------------------------------------------------
// Finalize: 1 block, 256 threads. Wave w handles batch w. Fixed-order sums
// -> deterministic. Fully overwrites all 8 outputs.
// ---------------------------------------------------------------------------
__global__ __launch_bounds__(256) void finalize_kernel(
    const float* __restrict__ ws,
    const float* __restrict__ tv,
    float* __restrict__ out)
{
    const int tid  = threadIdx.x;
    const int b    = tid >> 6;            // wave -> batch
    const int lane = tid & 63;

    // chamfer: 192 partials per batch (ws[b*192 .. b*192+191])
    const float* cp = ws + b * 192 + lane * 3;
    float s = cp[0] + cp[1] + cp[2];
#pragma unroll
    for (int off = 1; off < 64; off <<= 1)
        s += __shfl_xor(s, off);

    if (lane == 0) {
        out[b] = s * (1.0f / (NP * NV));
        // volume: 8 partials per batch
        const float* vp = ws + CHAM_BLOCKS + b * 8;
        float vs = ((vp[0] + vp[1]) + (vp[2] + vp[3])) +
                   ((vp[4] + vp[5]) + (vp[6] + vp[7]));
        float d = fabsf(vs) - tv[b];
        out[4 + b] = d * d;
    }
}

// ---------------------------------------------------------------------------
extern "C" void kernel_launch(void* const* d_in, const int* in_sizes, int n_in,
                              void* d_out, int out_size, void* d_ws, size_t ws_size,
                              hipStream_t stream) {
    const float* xs    = (const float*)d_in[0];
    const float* pm    = (const float*)d_in[1];
    const float* em    = (const float*)d_in[2];
    const int*   faces = (const int*)d_in[3];
    const float* tv    = (const float*)d_in[4];
    float* out = (float*)d_out;
    float* ws  = (float*)d_ws;            // 800 floats of partials

    fused_kernel<<<CHAM_BLOCKS + VOL_BLOCKS, 256, 0, stream>>>(xs, pm, em, faces, ws);
    finalize_kernel<<<1, 256, 0, stream>>>(ws, tv, out);
}